// Round 1
// baseline (4299.862 us; speedup 1.0000x reference)
//
#include <hip/hip_runtime.h>
#include <math.h>

#define NN 100000
#define NE 1600000
#define INC 128
#define DIM 64
#define EPS 1e-5f

// ---------------- per-channel stats (sum, sumsq) ----------------
template<int C>
__global__ __launch_bounds__(256) void stats_kernel(const float* __restrict__ in, int n, int stride,
                                                    float* __restrict__ sum_out, float* __restrict__ sq_out) {
    const int RPB = 256 / C;             // rows per block step
    int c  = threadIdx.x % C;
    int rl = threadIdx.x / C;
    int row = blockIdx.x * RPB + rl;
    int rstride = gridDim.x * RPB;
    float s = 0.f, q = 0.f;
    for (int r = row; r < n; r += rstride) {
        float v = in[(size_t)r * stride + c];
        s += v; q += v * v;
    }
    __shared__ float ls[256], lq[256];
    ls[threadIdx.x] = s; lq[threadIdx.x] = q;
    __syncthreads();
    if (rl == 0) {
        #pragma unroll
        for (int i = 1; i < RPB; i++) { s += ls[i * C + c]; q += lq[i * C + c]; }
        atomicAdd(&sum_out[c], s);
        atomicAdd(&sq_out[c], q);
    }
}

// scale = g*rsqrt(var+eps); shift = b - mean*scale   (launch with C threads)
__global__ void finalize_kernel(const float* __restrict__ sum, const float* __restrict__ sq,
                                const float* __restrict__ g, const float* __restrict__ b,
                                float n, float* __restrict__ scale, float* __restrict__ shift) {
    int c = threadIdx.x;
    float m = sum[c] / n;
    float v = sq[c] / n - m * m;
    float sc = g[c] * rsqrtf(v + EPS);
    scale[c] = sc;
    shift[c] = b[c] - m * sc;
}

// ---------------- edge scatter, layer 0 (128 ch, BN applied on the fly) ----------------
__global__ __launch_bounds__(256) void edge0_kernel(const float* __restrict__ X,
        const int* __restrict__ src, const int* __restrict__ dst, const float* __restrict__ ea,
        const float* __restrict__ scale, const float* __restrict__ shift,
        const float* __restrict__ We, const float* __restrict__ be,
        float* __restrict__ agg) {
    unsigned g = blockIdx.x * 256u + threadIdx.x;
    unsigned e = g >> 5;
    if (e >= NE) return;
    int c0 = (g & 31) * 4;
    int s = src[e], d = dst[e];
    float a = ea[e];
    float4 x  = *(const float4*)(X + (size_t)s * INC + c0);
    float4 sc = *(const float4*)(scale + c0);
    float4 sh = *(const float4*)(shift + c0);
    float4 wv = *(const float4*)(We + c0);
    float4 bv = *(const float4*)(be + c0);
    float v0 = fmaxf(fmaf(x.x, sc.x, sh.x) + fmaf(a, wv.x, bv.x), 0.f);
    float v1 = fmaxf(fmaf(x.y, sc.y, sh.y) + fmaf(a, wv.y, bv.y), 0.f);
    float v2 = fmaxf(fmaf(x.z, sc.z, sh.z) + fmaf(a, wv.z, bv.z), 0.f);
    float v3 = fmaxf(fmaf(x.w, sc.w, sh.w) + fmaf(a, wv.w, bv.w), 0.f);
    float* ap = agg + (size_t)d * INC + c0;
    atomicAdd(ap + 0, v0); atomicAdd(ap + 1, v1);
    atomicAdd(ap + 2, v2); atomicAdd(ap + 3, v3);
}

// ---------------- edge scatter, layer 1 (64 ch, h1 gathered from d_out stride 192) ----------------
__global__ __launch_bounds__(256) void edge1_kernel(const float* __restrict__ hprev,
        const int* __restrict__ src, const int* __restrict__ dst, const float* __restrict__ ea,
        const float* __restrict__ We, const float* __restrict__ be,
        float* __restrict__ agg) {
    unsigned g = blockIdx.x * 256u + threadIdx.x;
    unsigned e = g >> 4;
    if (e >= NE) return;
    int c0 = (g & 15) * 4;
    int s = src[e], d = dst[e];
    float a = ea[e];
    float4 h  = *(const float4*)(hprev + (size_t)s * 192 + c0);
    float4 wv = *(const float4*)(We + c0);
    float4 bv = *(const float4*)(be + c0);
    float v0 = fmaxf(h.x + fmaf(a, wv.x, bv.x), 0.f);
    float v1 = fmaxf(h.y + fmaf(a, wv.y, bv.y), 0.f);
    float v2 = fmaxf(h.z + fmaf(a, wv.z, bv.z), 0.f);
    float v3 = fmaxf(h.w + fmaf(a, wv.w, bv.w), 0.f);
    float* ap = agg + (size_t)d * DIM + c0;
    atomicAdd(ap + 0, v0); atomicAdd(ap + 1, v1);
    atomicAdd(ap + 2, v2); atomicAdd(ap + 3, v3);
}

// ---------------- node update layer 0: t1 = tanh((xhat+agg0) @ W0 + b0) -> d_out[:,0:64] ----------------
__global__ __launch_bounds__(256) void node0_kernel(const float* __restrict__ X, const float* __restrict__ agg,
        const float* __restrict__ scale, const float* __restrict__ shift,
        const float* __restrict__ W, const float* __restrict__ bvec,
        float* __restrict__ out) {
    __shared__ __align__(16) float u_s[64][INC + 4];   // [row][k], stride 132
    __shared__ __align__(16) float w_s[DIM][INC + 4];  // [col][k] transposed
    const int t = threadIdx.x;
    const int row0 = blockIdx.x * 64;
    for (int i = t; i < INC * DIM; i += 256) {
        int k = i >> 6, c = i & 63;
        w_s[c][k] = W[i];
    }
    for (int i = t; i < 64 * INC; i += 256) {
        int r = i >> 7, k = i & 127;
        int rr = row0 + r;
        float v = 0.f;
        if (rr < NN) {
            size_t idx = (size_t)rr * INC + k;
            v = fmaf(X[idx], scale[k], shift[k]) + agg[idx];
        }
        u_s[r][k] = v;
    }
    __syncthreads();
    const int cc = t & 15;          // cols cc, cc+16, cc+32, cc+48
    const int r0 = (t >> 4) << 2;   // 4 rows
    float acc[4][4];
    #pragma unroll
    for (int j = 0; j < 4; j++) {
        float bj = bvec[cc + 16 * j];
        acc[0][j] = bj; acc[1][j] = bj; acc[2][j] = bj; acc[3][j] = bj;
    }
    #pragma unroll 4
    for (int k = 0; k < INC; k += 4) {
        float4 w0 = *(const float4*)&w_s[cc][k];
        float4 w1 = *(const float4*)&w_s[cc + 16][k];
        float4 w2 = *(const float4*)&w_s[cc + 32][k];
        float4 w3 = *(const float4*)&w_s[cc + 48][k];
        #pragma unroll
        for (int i = 0; i < 4; i++) {
            float4 u = *(const float4*)&u_s[r0 + i][k];
            acc[i][0] = fmaf(u.x, w0.x, fmaf(u.y, w0.y, fmaf(u.z, w0.z, fmaf(u.w, w0.w, acc[i][0]))));
            acc[i][1] = fmaf(u.x, w1.x, fmaf(u.y, w1.y, fmaf(u.z, w1.z, fmaf(u.w, w1.w, acc[i][1]))));
            acc[i][2] = fmaf(u.x, w2.x, fmaf(u.y, w2.y, fmaf(u.z, w2.z, fmaf(u.w, w2.w, acc[i][2]))));
            acc[i][3] = fmaf(u.x, w3.x, fmaf(u.y, w3.y, fmaf(u.z, w3.z, fmaf(u.w, w3.w, acc[i][3]))));
        }
    }
    #pragma unroll
    for (int i = 0; i < 4; i++) {
        int rr = row0 + r0 + i;
        if (rr < NN) {
            #pragma unroll
            for (int j = 0; j < 4; j++)
                out[(size_t)rr * 192 + cc + 16 * j] = tanhf(acc[i][j]);
        }
    }
}

// ---------------- normalize t1 -> h1 in place (d_out[:,0:64]) ----------------
__global__ __launch_bounds__(256) void norm_h1_kernel(float* __restrict__ io,
        const float* __restrict__ scale, const float* __restrict__ shift) {
    size_t g = (size_t)blockIdx.x * 256 + threadIdx.x;
    size_t i4 = g * 4;
    if (i4 >= (size_t)NN * DIM) return;
    int c0 = (int)(i4 & 63);
    size_t n = i4 >> 6;
    float* p = io + n * 192 + c0;
    float4 v  = *(const float4*)p;
    float4 sc = *(const float4*)(scale + c0);
    float4 sh = *(const float4*)(shift + c0);
    v.x = fmaf(v.x, sc.x, sh.x);
    v.y = fmaf(v.y, sc.y, sh.y);
    v.z = fmaf(v.z, sc.z, sh.z);
    v.w = fmaf(v.w, sc.w, sh.w);
    *(float4*)p = v;
}

// ---------------- node update layer 1: t2 = tanh((h1+agg1) @ W1 + b1) -> d_out[:,64:128] ----------------
__global__ __launch_bounds__(256) void node1_kernel(const float* __restrict__ hprev, const float* __restrict__ agg,
        const float* __restrict__ W, const float* __restrict__ bvec,
        float* __restrict__ out) {
    __shared__ __align__(16) float u_s[64][DIM + 4];   // stride 68
    __shared__ __align__(16) float w_s[DIM][DIM + 4];
    const int t = threadIdx.x;
    const int row0 = blockIdx.x * 64;
    for (int i = t; i < DIM * DIM; i += 256) {
        int k = i >> 6, c = i & 63;
        w_s[c][k] = W[i];
    }
    for (int i = t; i < 64 * DIM; i += 256) {
        int r = i >> 6, k = i & 63;
        int rr = row0 + r;
        float v = 0.f;
        if (rr < NN)
            v = hprev[(size_t)rr * 192 + k] + agg[(size_t)rr * DIM + k];
        u_s[r][k] = v;
    }
    __syncthreads();
    const int cc = t & 15;
    const int r0 = (t >> 4) << 2;
    float acc[4][4];
    #pragma unroll
    for (int j = 0; j < 4; j++) {
        float bj = bvec[cc + 16 * j];
        acc[0][j] = bj; acc[1][j] = bj; acc[2][j] = bj; acc[3][j] = bj;
    }
    #pragma unroll 4
    for (int k = 0; k < DIM; k += 4) {
        float4 w0 = *(const float4*)&w_s[cc][k];
        float4 w1 = *(const float4*)&w_s[cc + 16][k];
        float4 w2 = *(const float4*)&w_s[cc + 32][k];
        float4 w3 = *(const float4*)&w_s[cc + 48][k];
        #pragma unroll
        for (int i = 0; i < 4; i++) {
            float4 u = *(const float4*)&u_s[r0 + i][k];
            acc[i][0] = fmaf(u.x, w0.x, fmaf(u.y, w0.y, fmaf(u.z, w0.z, fmaf(u.w, w0.w, acc[i][0]))));
            acc[i][1] = fmaf(u.x, w1.x, fmaf(u.y, w1.y, fmaf(u.z, w1.z, fmaf(u.w, w1.w, acc[i][1]))));
            acc[i][2] = fmaf(u.x, w2.x, fmaf(u.y, w2.y, fmaf(u.z, w2.z, fmaf(u.w, w2.w, acc[i][2]))));
            acc[i][3] = fmaf(u.x, w3.x, fmaf(u.y, w3.y, fmaf(u.z, w3.z, fmaf(u.w, w3.w, acc[i][3]))));
        }
    }
    #pragma unroll
    for (int i = 0; i < 4; i++) {
        int rr = row0 + r0 + i;
        if (rr < NN) {
            #pragma unroll
            for (int j = 0; j < 4; j++)
                out[(size_t)rr * 192 + 64 + cc + 16 * j] = tanhf(acc[i][j]);
        }
    }
}

// ---------------- fused: h2 = BN(t2) (in place), h3 = tanh(h2 @ Wfc) -> d_out[:,128:192] ----------------
__global__ __launch_bounds__(256) void fc_kernel(float* __restrict__ io,
        const float* __restrict__ scale, const float* __restrict__ shift,
        const float* __restrict__ W) {
    __shared__ __align__(16) float u_s[64][DIM + 4];
    __shared__ __align__(16) float w_s[DIM][DIM + 4];
    const int t = threadIdx.x;
    const int row0 = blockIdx.x * 64;
    for (int i = t; i < DIM * DIM; i += 256) {
        int k = i >> 6, c = i & 63;
        w_s[c][k] = W[i];
    }
    for (int i = t; i < 64 * DIM; i += 256) {
        int r = i >> 6, k = i & 63;
        int rr = row0 + r;
        float v = 0.f;
        if (rr < NN) {
            size_t idx = (size_t)rr * 192 + 64 + k;
            v = fmaf(io[idx], scale[k], shift[k]);
            io[idx] = v;                       // h2
        }
        u_s[r][k] = v;
    }
    __syncthreads();
    const int cc = t & 15;
    const int r0 = (t >> 4) << 2;
    float acc[4][4];
    #pragma unroll
    for (int j = 0; j < 4; j++) { acc[0][j] = 0.f; acc[1][j] = 0.f; acc[2][j] = 0.f; acc[3][j] = 0.f; }
    #pragma unroll 4
    for (int k = 0; k < DIM; k += 4) {
        float4 w0 = *(const float4*)&w_s[cc][k];
        float4 w1 = *(const float4*)&w_s[cc + 16][k];
        float4 w2 = *(const float4*)&w_s[cc + 32][k];
        float4 w3 = *(const float4*)&w_s[cc + 48][k];
        #pragma unroll
        for (int i = 0; i < 4; i++) {
            float4 u = *(const float4*)&u_s[r0 + i][k];
            acc[i][0] = fmaf(u.x, w0.x, fmaf(u.y, w0.y, fmaf(u.z, w0.z, fmaf(u.w, w0.w, acc[i][0]))));
            acc[i][1] = fmaf(u.x, w1.x, fmaf(u.y, w1.y, fmaf(u.z, w1.z, fmaf(u.w, w1.w, acc[i][1]))));
            acc[i][2] = fmaf(u.x, w2.x, fmaf(u.y, w2.y, fmaf(u.z, w2.z, fmaf(u.w, w2.w, acc[i][2]))));
            acc[i][3] = fmaf(u.x, w3.x, fmaf(u.y, w3.y, fmaf(u.z, w3.z, fmaf(u.w, w3.w, acc[i][3]))));
        }
    }
    #pragma unroll
    for (int i = 0; i < 4; i++) {
        int rr = row0 + r0 + i;
        if (rr < NN) {
            #pragma unroll
            for (int j = 0; j < 4; j++)
                io[(size_t)rr * 192 + 128 + cc + 16 * j] = tanhf(acc[i][j]);
        }
    }
}

extern "C" void kernel_launch(void* const* d_in, const int* in_sizes, int n_in,
                              void* d_out, int out_size, void* d_ws, size_t ws_size,
                              hipStream_t stream) {
    const float* X      = (const float*)d_in[0];
    const int*   ei     = (const int*)  d_in[1];
    const float* ea     = (const float*)d_in[2];
    const float* bng    = (const float*)d_in[3];
    const float* bnb    = (const float*)d_in[4];
    const float* We0    = (const float*)d_in[5];
    const float* be0    = (const float*)d_in[6];
    const float* W0     = (const float*)d_in[7];
    const float* b0     = (const float*)d_in[8];
    const float* bn0g   = (const float*)d_in[9];
    const float* bn0b   = (const float*)d_in[10];
    const float* We1    = (const float*)d_in[11];
    const float* be1    = (const float*)d_in[12];
    const float* W1     = (const float*)d_in[13];
    const float* b1     = (const float*)d_in[14];
    const float* bn1g   = (const float*)d_in[15];
    const float* bn1b   = (const float*)d_in[16];
    const float* Wfc    = (const float*)d_in[17];

    const int* src = ei;
    const int* dst = ei + NE;
    float* out = (float*)d_out;

    float* ws   = (float*)d_ws;
    float* agg0 = ws;                               // NN*INC = 12.8M floats
    float* agg1 = agg0 + (size_t)NN * INC;          // NN*DIM = 6.4M floats
    float* st   = agg1 + (size_t)NN * DIM;          // 1024 floats of stats
    float* sum_in = st,       *sq_in = st + 128, *scale_in = st + 256, *shift_in = st + 384;
    float* sum0   = st + 512, *sq0   = st + 576, *scale0   = st + 640, *shift0   = st + 704;
    float* sum1   = st + 768, *sq1   = st + 832, *scale1   = st + 896, *shift1   = st + 960;

    // zero accumulators + stats (poisoned to 0xAA once; not re-poisoned between replays)
    hipMemsetAsync(ws, 0, ((size_t)NN * INC + (size_t)NN * DIM + 1024) * sizeof(float), stream);

    // input BN
    stats_kernel<INC><<<512, 256, 0, stream>>>(X, NN, INC, sum_in, sq_in);
    finalize_kernel<<<1, INC, 0, stream>>>(sum_in, sq_in, bng, bnb, (float)NN, scale_in, shift_in);

    // layer 0
    edge0_kernel<<<NE * 32 / 256, 256, 0, stream>>>(X, src, dst, ea, scale_in, shift_in, We0, be0, agg0);
    node0_kernel<<<(NN + 63) / 64, 256, 0, stream>>>(X, agg0, scale_in, shift_in, W0, b0, out);
    stats_kernel<DIM><<<512, 256, 0, stream>>>(out, NN, 192, sum0, sq0);
    finalize_kernel<<<1, DIM, 0, stream>>>(sum0, sq0, bn0g, bn0b, (float)NN, scale0, shift0);
    norm_h1_kernel<<<(NN * DIM / 4 + 255) / 256, 256, 0, stream>>>(out, scale0, shift0);

    // layer 1
    edge1_kernel<<<NE * 16 / 256, 256, 0, stream>>>(out, src, dst, ea, We1, be1, agg1);
    node1_kernel<<<(NN + 63) / 64, 256, 0, stream>>>(out, agg1, W1, b1, out);
    stats_kernel<DIM><<<512, 256, 0, stream>>>(out + 64, NN, 192, sum1, sq1);
    finalize_kernel<<<1, DIM, 0, stream>>>(sum1, sq1, bn1g, bn1b, (float)NN, scale1, shift1);

    // h2 (in place) + h3
    fc_kernel<<<(NN + 63) / 64, 256, 0, stream>>>(out, scale1, shift1, Wfc);
}

// Round 2
// 601.336 us; speedup vs baseline: 7.1505x; 7.1505x over previous
//
#include <hip/hip_runtime.h>
#include <math.h>
#include <stdint.h>

#define NN 100000
#define NE 1600000
#define INC 128
#define DIM 64
#define EPS 1e-5f

// ---------------- per-channel stats (sum, sumsq) in f64 ----------------
template<int C>
__global__ __launch_bounds__(256) void stats_kernel(const float* __restrict__ in, int n, int stride,
                                                    double* __restrict__ sum_out, double* __restrict__ sq_out) {
    const int RPB = 256 / C;             // rows per block step
    int c  = threadIdx.x % C;
    int rl = threadIdx.x / C;
    int row = blockIdx.x * RPB + rl;
    int rstride = gridDim.x * RPB;
    double s = 0.0, q = 0.0;
    for (int r = row; r < n; r += rstride) {
        double v = (double)in[(size_t)r * stride + c];
        s += v; q += v * v;
    }
    __shared__ double ls[256], lq[256];
    ls[threadIdx.x] = s; lq[threadIdx.x] = q;
    __syncthreads();
    if (rl == 0) {
        #pragma unroll
        for (int i = 1; i < RPB; i++) { s += ls[i * C + c]; q += lq[i * C + c]; }
        atomicAdd(&sum_out[c], s);
        atomicAdd(&sq_out[c], q);
    }
}

// scale = g*rsqrt(var+eps); shift = b - mean*scale   (launch with C threads)
__global__ void finalize_kernel(const double* __restrict__ sum, const double* __restrict__ sq,
                                const float* __restrict__ g, const float* __restrict__ b,
                                double n, float* __restrict__ scale, float* __restrict__ shift) {
    int c = threadIdx.x;
    double m = sum[c] / n;
    double v = sq[c] / n - m * m;
    double sc = (double)g[c] / sqrt(v + (double)EPS);
    scale[c] = (float)sc;
    shift[c] = (float)((double)b[c] - m * sc);
}

// ---------------- CSR build: histogram / scan / scatter ----------------
__global__ __launch_bounds__(256) void hist_kernel(const int* __restrict__ dst, int* __restrict__ counts) {
    int e = blockIdx.x * 256 + threadIdx.x;
    if (e < NE) atomicAdd(&counts[dst[e]], 1);
}

// block-local exclusive scan of counts (1024/block), block sums out
__global__ __launch_bounds__(1024) void scan1_kernel(const int* __restrict__ counts,
                                                     int* __restrict__ offs, int* __restrict__ bsums) {
    __shared__ int tmp[2][1024];
    int t = threadIdx.x;
    int g = blockIdx.x * 1024 + t;
    int v = (g < NN) ? counts[g] : 0;
    tmp[0][t] = v;
    __syncthreads();
    int pin = 0;
    for (int d = 1; d < 1024; d <<= 1) {
        int x = tmp[pin][t] + ((t >= d) ? tmp[pin][t - d] : 0);
        tmp[pin ^ 1][t] = x;
        pin ^= 1;
        __syncthreads();
    }
    int incl = tmp[pin][t];
    if (g < NN) offs[g] = incl - v;          // exclusive within block
    if (t == 1023) bsums[blockIdx.x] = incl; // block total
}

// exclusive scan of block sums (single block, NB<=128)
__global__ __launch_bounds__(128) void scan2_kernel(int* __restrict__ bsums, int nb) {
    __shared__ int tmp[2][128];
    int t = threadIdx.x;
    int v = (t < nb) ? bsums[t] : 0;
    tmp[0][t] = v;
    __syncthreads();
    int pin = 0;
    for (int d = 1; d < 128; d <<= 1) {
        int x = tmp[pin][t] + ((t >= d) ? tmp[pin][t - d] : 0);
        tmp[pin ^ 1][t] = x;
        pin ^= 1;
        __syncthreads();
    }
    if (t < nb) bsums[t] = tmp[pin][t] - v;  // exclusive
}

__global__ __launch_bounds__(256) void scan3_kernel(int* __restrict__ offs, const int* __restrict__ bsums,
                                                    int* __restrict__ cursor) {
    int g = blockIdx.x * 256 + threadIdx.x;
    if (g < NN) {
        int o = offs[g] + bsums[g >> 10];
        offs[g] = o;
        cursor[g] = o;
    }
    if (g == 0) offs[NN] = NE;
}

__global__ __launch_bounds__(256) void scatter_kernel(const int* __restrict__ src, const int* __restrict__ dst,
                                                      const float* __restrict__ ea, int* __restrict__ cursor,
                                                      int* __restrict__ src_s, float* __restrict__ ea_s) {
    int e = blockIdx.x * 256 + threadIdx.x;
    if (e >= NE) return;
    int d = dst[e];
    int pos = atomicAdd(&cursor[d], 1);
    src_s[pos] = src[e];
    ea_s[pos] = ea[e];
}

// ---------------- layer-0 aggregation (gather side, no atomics) ----------------
// one wave per node; lane l owns channels 2l,2l+1. u0 = xhat + sum relu(xhat[src]+a*We+be)
__global__ __launch_bounds__(256) void agg0_kernel(const float* __restrict__ X, const int* __restrict__ offs,
        const int* __restrict__ src_s, const float* __restrict__ ea_s,
        const float* __restrict__ scale, const float* __restrict__ shift,
        const float* __restrict__ We, const float* __restrict__ be,
        float* __restrict__ u0) {
    int wid = threadIdx.x >> 6;
    int l   = threadIdx.x & 63;
    int n = blockIdx.x * 4 + wid;
    if (n >= NN) return;
    int c = l * 2;
    float2 sc = *(const float2*)(scale + c);
    float2 sh = *(const float2*)(shift + c);
    float2 wv = *(const float2*)(We + c);
    float2 bv = *(const float2*)(be + c);
    float2 x  = *(const float2*)(X + (size_t)n * INC + c);
    float a0 = fmaf(x.x, sc.x, sh.x);
    float a1 = fmaf(x.y, sc.y, sh.y);
    int beg = offs[n], end = offs[n + 1];
    for (int base = beg; base < end; base += 64) {
        int j = base + l;
        int s = 0; float av = 0.f;
        if (j < end) { s = src_s[j]; av = ea_s[j]; }
        int cnt = min(64, end - base);
        int t = 0;
        for (; t + 4 <= cnt; t += 4) {
            int s0 = __shfl(s, t), s1 = __shfl(s, t + 1), s2 = __shfl(s, t + 2), s3 = __shfl(s, t + 3);
            float e0 = __shfl(av, t), e1 = __shfl(av, t + 1), e2 = __shfl(av, t + 2), e3 = __shfl(av, t + 3);
            float2 x0 = *(const float2*)(X + (size_t)s0 * INC + c);
            float2 x1 = *(const float2*)(X + (size_t)s1 * INC + c);
            float2 x2 = *(const float2*)(X + (size_t)s2 * INC + c);
            float2 x3 = *(const float2*)(X + (size_t)s3 * INC + c);
            a0 += fmaxf(fmaf(x0.x, sc.x, sh.x) + fmaf(e0, wv.x, bv.x), 0.f);
            a1 += fmaxf(fmaf(x0.y, sc.y, sh.y) + fmaf(e0, wv.y, bv.y), 0.f);
            a0 += fmaxf(fmaf(x1.x, sc.x, sh.x) + fmaf(e1, wv.x, bv.x), 0.f);
            a1 += fmaxf(fmaf(x1.y, sc.y, sh.y) + fmaf(e1, wv.y, bv.y), 0.f);
            a0 += fmaxf(fmaf(x2.x, sc.x, sh.x) + fmaf(e2, wv.x, bv.x), 0.f);
            a1 += fmaxf(fmaf(x2.y, sc.y, sh.y) + fmaf(e2, wv.y, bv.y), 0.f);
            a0 += fmaxf(fmaf(x3.x, sc.x, sh.x) + fmaf(e3, wv.x, bv.x), 0.f);
            a1 += fmaxf(fmaf(x3.y, sc.y, sh.y) + fmaf(e3, wv.y, bv.y), 0.f);
        }
        for (; t < cnt; ++t) {
            int ss = __shfl(s, t);
            float aa = __shfl(av, t);
            float2 xv = *(const float2*)(X + (size_t)ss * INC + c);
            a0 += fmaxf(fmaf(xv.x, sc.x, sh.x) + fmaf(aa, wv.x, bv.x), 0.f);
            a1 += fmaxf(fmaf(xv.y, sc.y, sh.y) + fmaf(aa, wv.y, bv.y), 0.f);
        }
    }
    *(float2*)(u0 + (size_t)n * INC + c) = make_float2(a0, a1);
}

// ---------------- layer-1 aggregation: u1 = h1 + sum relu(h1[src]+a*We1+be1) ----------------
__global__ __launch_bounds__(256) void agg1_kernel(const float* __restrict__ h1, const int* __restrict__ offs,
        const int* __restrict__ src_s, const float* __restrict__ ea_s,
        const float* __restrict__ We, const float* __restrict__ be,
        float* __restrict__ u1) {
    int wid = threadIdx.x >> 6;
    int l   = threadIdx.x & 63;
    int n = blockIdx.x * 4 + wid;
    if (n >= NN) return;
    float wv = We[l];
    float bv = be[l];
    float acc = h1[(size_t)n * 192 + l];
    int beg = offs[n], end = offs[n + 1];
    for (int base = beg; base < end; base += 64) {
        int j = base + l;
        int s = 0; float av = 0.f;
        if (j < end) { s = src_s[j]; av = ea_s[j]; }
        int cnt = min(64, end - base);
        int t = 0;
        for (; t + 4 <= cnt; t += 4) {
            int s0 = __shfl(s, t), s1 = __shfl(s, t + 1), s2 = __shfl(s, t + 2), s3 = __shfl(s, t + 3);
            float e0 = __shfl(av, t), e1 = __shfl(av, t + 1), e2 = __shfl(av, t + 2), e3 = __shfl(av, t + 3);
            float h0 = h1[(size_t)s0 * 192 + l];
            float hA = h1[(size_t)s1 * 192 + l];
            float hB = h1[(size_t)s2 * 192 + l];
            float hC = h1[(size_t)s3 * 192 + l];
            acc += fmaxf(h0 + fmaf(e0, wv, bv), 0.f);
            acc += fmaxf(hA + fmaf(e1, wv, bv), 0.f);
            acc += fmaxf(hB + fmaf(e2, wv, bv), 0.f);
            acc += fmaxf(hC + fmaf(e3, wv, bv), 0.f);
        }
        for (; t < cnt; ++t) {
            int ss = __shfl(s, t);
            float aa = __shfl(av, t);
            acc += fmaxf(h1[(size_t)ss * 192 + l] + fmaf(aa, wv, bv), 0.f);
        }
    }
    u1[(size_t)n * DIM + l] = acc;
}

// ---------------- node update layer 0: t1 = tanh(u0 @ W0 + b0) -> d_out[:,0:64] ----------------
__global__ __launch_bounds__(256) void node0_kernel(const float* __restrict__ u0,
        const float* __restrict__ W, const float* __restrict__ bvec,
        float* __restrict__ out) {
    __shared__ __align__(16) float u_s[64][INC + 4];   // stride 132
    __shared__ __align__(16) float w_s[DIM][INC + 4];
    const int t = threadIdx.x;
    const int row0 = blockIdx.x * 64;
    for (int i = t; i < INC * DIM; i += 256) {
        int k = i >> 6, c = i & 63;
        w_s[c][k] = W[i];
    }
    for (int i = t; i < 64 * (INC / 4); i += 256) {
        int r = i >> 5, k4 = (i & 31) << 2;
        int rr = row0 + r;
        float4 v = make_float4(0.f, 0.f, 0.f, 0.f);
        if (rr < NN) v = *(const float4*)(u0 + (size_t)rr * INC + k4);
        *(float4*)&u_s[r][k4] = v;
    }
    __syncthreads();
    const int cc = t & 15;
    const int r0 = (t >> 4) << 2;
    float acc[4][4];
    #pragma unroll
    for (int j = 0; j < 4; j++) {
        float bj = bvec[cc + 16 * j];
        acc[0][j] = bj; acc[1][j] = bj; acc[2][j] = bj; acc[3][j] = bj;
    }
    #pragma unroll 4
    for (int k = 0; k < INC; k += 4) {
        float4 w0 = *(const float4*)&w_s[cc][k];
        float4 w1 = *(const float4*)&w_s[cc + 16][k];
        float4 w2 = *(const float4*)&w_s[cc + 32][k];
        float4 w3 = *(const float4*)&w_s[cc + 48][k];
        #pragma unroll
        for (int i = 0; i < 4; i++) {
            float4 u = *(const float4*)&u_s[r0 + i][k];
            acc[i][0] = fmaf(u.x, w0.x, fmaf(u.y, w0.y, fmaf(u.z, w0.z, fmaf(u.w, w0.w, acc[i][0]))));
            acc[i][1] = fmaf(u.x, w1.x, fmaf(u.y, w1.y, fmaf(u.z, w1.z, fmaf(u.w, w1.w, acc[i][1]))));
            acc[i][2] = fmaf(u.x, w2.x, fmaf(u.y, w2.y, fmaf(u.z, w2.z, fmaf(u.w, w2.w, acc[i][2]))));
            acc[i][3] = fmaf(u.x, w3.x, fmaf(u.y, w3.y, fmaf(u.z, w3.z, fmaf(u.w, w3.w, acc[i][3]))));
        }
    }
    #pragma unroll
    for (int i = 0; i < 4; i++) {
        int rr = row0 + r0 + i;
        if (rr < NN) {
            #pragma unroll
            for (int j = 0; j < 4; j++)
                out[(size_t)rr * 192 + cc + 16 * j] = tanhf(acc[i][j]);
        }
    }
}

// ---------------- normalize t1 -> h1 in place (d_out[:,0:64]) ----------------
__global__ __launch_bounds__(256) void norm_h1_kernel(float* __restrict__ io,
        const float* __restrict__ scale, const float* __restrict__ shift) {
    size_t g = (size_t)blockIdx.x * 256 + threadIdx.x;
    size_t i4 = g * 4;
    if (i4 >= (size_t)NN * DIM) return;
    int c0 = (int)(i4 & 63);
    size_t n = i4 >> 6;
    float* p = io + n * 192 + c0;
    float4 v  = *(const float4*)p;
    float4 sc = *(const float4*)(scale + c0);
    float4 sh = *(const float4*)(shift + c0);
    v.x = fmaf(v.x, sc.x, sh.x);
    v.y = fmaf(v.y, sc.y, sh.y);
    v.z = fmaf(v.z, sc.z, sh.z);
    v.w = fmaf(v.w, sc.w, sh.w);
    *(float4*)p = v;
}

// ---------------- node update layer 1: t2 = tanh(u1 @ W1 + b1) -> d_out[:,64:128] ----------------
__global__ __launch_bounds__(256) void node1_kernel(const float* __restrict__ u1,
        const float* __restrict__ W, const float* __restrict__ bvec,
        float* __restrict__ out) {
    __shared__ __align__(16) float u_s[64][DIM + 4];   // stride 68
    __shared__ __align__(16) float w_s[DIM][DIM + 4];
    const int t = threadIdx.x;
    const int row0 = blockIdx.x * 64;
    for (int i = t; i < DIM * DIM; i += 256) {
        int k = i >> 6, c = i & 63;
        w_s[c][k] = W[i];
    }
    for (int i = t; i < 64 * (DIM / 4); i += 256) {
        int r = i >> 4, k4 = (i & 15) << 2;
        int rr = row0 + r;
        float4 v = make_float4(0.f, 0.f, 0.f, 0.f);
        if (rr < NN) v = *(const float4*)(u1 + (size_t)rr * DIM + k4);
        *(float4*)&u_s[r][k4] = v;
    }
    __syncthreads();
    const int cc = t & 15;
    const int r0 = (t >> 4) << 2;
    float acc[4][4];
    #pragma unroll
    for (int j = 0; j < 4; j++) {
        float bj = bvec[cc + 16 * j];
        acc[0][j] = bj; acc[1][j] = bj; acc[2][j] = bj; acc[3][j] = bj;
    }
    #pragma unroll 4
    for (int k = 0; k < DIM; k += 4) {
        float4 w0 = *(const float4*)&w_s[cc][k];
        float4 w1 = *(const float4*)&w_s[cc + 16][k];
        float4 w2 = *(const float4*)&w_s[cc + 32][k];
        float4 w3 = *(const float4*)&w_s[cc + 48][k];
        #pragma unroll
        for (int i = 0; i < 4; i++) {
            float4 u = *(const float4*)&u_s[r0 + i][k];
            acc[i][0] = fmaf(u.x, w0.x, fmaf(u.y, w0.y, fmaf(u.z, w0.z, fmaf(u.w, w0.w, acc[i][0]))));
            acc[i][1] = fmaf(u.x, w1.x, fmaf(u.y, w1.y, fmaf(u.z, w1.z, fmaf(u.w, w1.w, acc[i][1]))));
            acc[i][2] = fmaf(u.x, w2.x, fmaf(u.y, w2.y, fmaf(u.z, w2.z, fmaf(u.w, w2.w, acc[i][2]))));
            acc[i][3] = fmaf(u.x, w3.x, fmaf(u.y, w3.y, fmaf(u.z, w3.z, fmaf(u.w, w3.w, acc[i][3]))));
        }
    }
    #pragma unroll
    for (int i = 0; i < 4; i++) {
        int rr = row0 + r0 + i;
        if (rr < NN) {
            #pragma unroll
            for (int j = 0; j < 4; j++)
                out[(size_t)rr * 192 + 64 + cc + 16 * j] = tanhf(acc[i][j]);
        }
    }
}

// ---------------- fused: h2 = BN(t2) (in place), h3 = tanh(h2 @ Wfc) -> d_out[:,128:192] ----------------
__global__ __launch_bounds__(256) void fc_kernel(float* __restrict__ io,
        const float* __restrict__ scale, const float* __restrict__ shift,
        const float* __restrict__ W) {
    __shared__ __align__(16) float u_s[64][DIM + 4];
    __shared__ __align__(16) float w_s[DIM][DIM + 4];
    const int t = threadIdx.x;
    const int row0 = blockIdx.x * 64;
    for (int i = t; i < DIM * DIM; i += 256) {
        int k = i >> 6, c = i & 63;
        w_s[c][k] = W[i];
    }
    for (int i = t; i < 64 * DIM; i += 256) {
        int r = i >> 6, k = i & 63;
        int rr = row0 + r;
        float v = 0.f;
        if (rr < NN) {
            size_t idx = (size_t)rr * 192 + 64 + k;
            v = fmaf(io[idx], scale[k], shift[k]);
            io[idx] = v;                       // h2
        }
        u_s[r][k] = v;
    }
    __syncthreads();
    const int cc = t & 15;
    const int r0 = (t >> 4) << 2;
    float acc[4][4];
    #pragma unroll
    for (int j = 0; j < 4; j++) { acc[0][j] = 0.f; acc[1][j] = 0.f; acc[2][j] = 0.f; acc[3][j] = 0.f; }
    #pragma unroll 4
    for (int k = 0; k < DIM; k += 4) {
        float4 w0 = *(const float4*)&w_s[cc][k];
        float4 w1 = *(const float4*)&w_s[cc + 16][k];
        float4 w2 = *(const float4*)&w_s[cc + 32][k];
        float4 w3 = *(const float4*)&w_s[cc + 48][k];
        #pragma unroll
        for (int i = 0; i < 4; i++) {
            float4 u = *(const float4*)&u_s[r0 + i][k];
            acc[i][0] = fmaf(u.x, w0.x, fmaf(u.y, w0.y, fmaf(u.z, w0.z, fmaf(u.w, w0.w, acc[i][0]))));
            acc[i][1] = fmaf(u.x, w1.x, fmaf(u.y, w1.y, fmaf(u.z, w1.z, fmaf(u.w, w1.w, acc[i][1]))));
            acc[i][2] = fmaf(u.x, w2.x, fmaf(u.y, w2.y, fmaf(u.z, w2.z, fmaf(u.w, w2.w, acc[i][2]))));
            acc[i][3] = fmaf(u.x, w3.x, fmaf(u.y, w3.y, fmaf(u.z, w3.z, fmaf(u.w, w3.w, acc[i][3]))));
        }
    }
    #pragma unroll
    for (int i = 0; i < 4; i++) {
        int rr = row0 + r0 + i;
        if (rr < NN) {
            #pragma unroll
            for (int j = 0; j < 4; j++)
                io[(size_t)rr * 192 + 128 + cc + 16 * j] = tanhf(acc[i][j]);
        }
    }
}

extern "C" void kernel_launch(void* const* d_in, const int* in_sizes, int n_in,
                              void* d_out, int out_size, void* d_ws, size_t ws_size,
                              hipStream_t stream) {
    const float* X      = (const float*)d_in[0];
    const int*   ei     = (const int*)  d_in[1];
    const float* ea     = (const float*)d_in[2];
    const float* bng    = (const float*)d_in[3];
    const float* bnb    = (const float*)d_in[4];
    const float* We0    = (const float*)d_in[5];
    const float* be0    = (const float*)d_in[6];
    const float* W0     = (const float*)d_in[7];
    const float* b0     = (const float*)d_in[8];
    const float* bn0g   = (const float*)d_in[9];
    const float* bn0b   = (const float*)d_in[10];
    const float* We1    = (const float*)d_in[11];
    const float* be1    = (const float*)d_in[12];
    const float* W1     = (const float*)d_in[13];
    const float* b1     = (const float*)d_in[14];
    const float* bn1g   = (const float*)d_in[15];
    const float* bn1b   = (const float*)d_in[16];
    const float* Wfc    = (const float*)d_in[17];

    const int* src = ei;
    const int* dst = ei + NE;
    float* out = (float*)d_out;

    // ---- workspace layout (~66 MB) ----
    float* u0     = (float*)d_ws;                       // NN*INC floats; u1 aliases front part
    float* u1     = u0;                                 // (u0 dead after node0)
    int*   src_s  = (int*)(u0 + (size_t)NN * INC);      // NE
    float* ea_s   = (float*)(src_s + NE);               // NE
    int*   counts = (int*)(ea_s + NE);                  // NN
    int*   offs   = counts + NN;                        // NN+1
    int*   cursor = offs + NN + 1;                      // NN
    int*   bsums  = cursor + NN;                        // 128
    double* dstats = (double*)(((uintptr_t)(bsums + 128) + 15) & ~(uintptr_t)15);
    double* dsum_in = dstats;        double* dsq_in = dstats + 128;
    double* dsum0   = dstats + 256;  double* dsq0   = dstats + 320;
    double* dsum1   = dstats + 384;  double* dsq1   = dstats + 448;
    float* fst = (float*)(dstats + 512);
    float *scale_in = fst,       *shift_in = fst + 128;
    float *scale0   = fst + 256, *shift0   = fst + 320;
    float *scale1   = fst + 384, *shift1   = fst + 448;

    // zero only what must be zero each call
    hipMemsetAsync(counts, 0, NN * sizeof(int), stream);
    hipMemsetAsync(dstats, 0, 512 * sizeof(double), stream);

    // input BN stats
    stats_kernel<INC><<<512, 256, 0, stream>>>(X, NN, INC, dsum_in, dsq_in);
    finalize_kernel<<<1, INC, 0, stream>>>(dsum_in, dsq_in, bng, bnb, (double)NN, scale_in, shift_in);

    // CSR build (shared by both layers)
    const int NB = (NN + 1023) / 1024;   // 98
    hist_kernel<<<NE / 256, 256, 0, stream>>>(dst, counts);
    scan1_kernel<<<NB, 1024, 0, stream>>>(counts, offs, bsums);
    scan2_kernel<<<1, 128, 0, stream>>>(bsums, NB);
    scan3_kernel<<<(NN + 255) / 256, 256, 0, stream>>>(offs, bsums, cursor);
    scatter_kernel<<<NE / 256, 256, 0, stream>>>(src, dst, ea, cursor, src_s, ea_s);

    // layer 0
    agg0_kernel<<<(NN + 3) / 4, 256, 0, stream>>>(X, offs, src_s, ea_s, scale_in, shift_in, We0, be0, u0);
    node0_kernel<<<(NN + 63) / 64, 256, 0, stream>>>(u0, W0, b0, out);
    stats_kernel<DIM><<<512, 256, 0, stream>>>(out, NN, 192, dsum0, dsq0);
    finalize_kernel<<<1, DIM, 0, stream>>>(dsum0, dsq0, bn0g, bn0b, (double)NN, scale0, shift0);
    norm_h1_kernel<<<(NN * DIM / 4 + 255) / 256, 256, 0, stream>>>(out, scale0, shift0);

    // layer 1
    agg1_kernel<<<(NN + 3) / 4, 256, 0, stream>>>(out, offs, src_s, ea_s, We1, be1, u1);
    node1_kernel<<<(NN + 63) / 64, 256, 0, stream>>>(u1, W1, b1, out);
    stats_kernel<DIM><<<512, 256, 0, stream>>>(out + 64, NN, 192, dsum1, dsq1);
    finalize_kernel<<<1, DIM, 0, stream>>>(dsum1, dsq1, bn1g, bn1b, (double)NN, scale1, shift1);

    // h2 (in place) + h3
    fc_kernel<<<(NN + 63) / 64, 256, 0, stream>>>(out, scale1, shift1, Wfc);
}

// Round 3
// 600.612 us; speedup vs baseline: 7.1591x; 1.0012x over previous
//
#include <hip/hip_runtime.h>
#include <math.h>
#include <stdint.h>

#define NN 100000
#define NE 1600000
#define INC 128
#define DIM 64
#define EPS 1e-5f

// ---------------- per-channel stats (sum, sumsq) in f64 ----------------
template<int C>
__global__ __launch_bounds__(256) void stats_kernel(const float* __restrict__ in, int n, int stride,
                                                    double* __restrict__ sum_out, double* __restrict__ sq_out) {
    const int RPB = 256 / C;             // rows per block step
    int c  = threadIdx.x % C;
    int rl = threadIdx.x / C;
    int row = blockIdx.x * RPB + rl;
    int rstride = gridDim.x * RPB;
    double s = 0.0, q = 0.0;
    for (int r = row; r < n; r += rstride) {
        double v = (double)in[(size_t)r * stride + c];
        s += v; q += v * v;
    }
    __shared__ double ls[256], lq[256];
    ls[threadIdx.x] = s; lq[threadIdx.x] = q;
    __syncthreads();
    if (rl == 0) {
        #pragma unroll
        for (int i = 1; i < RPB; i++) { s += ls[i * C + c]; q += lq[i * C + c]; }
        atomicAdd(&sum_out[c], s);
        atomicAdd(&sq_out[c], q);
    }
}

// BN scale/shift from f64 stats (device helper, computed redundantly per block)
__device__ inline void bn_fold(int t, int C, const double* dsum, const double* dsq,
                               const float* g, const float* b, float* sc_s, float* sh_s) {
    if (t < C) {
        double m = dsum[t] / (double)NN;
        double v = dsq[t] / (double)NN - m * m;
        double sc = (double)g[t] / sqrt(v + (double)EPS);
        sc_s[t] = (float)sc;
        sh_s[t] = (float)((double)b[t] - m * sc);
    }
}

// ---------------- CSR build: histogram / scan / scatter ----------------
__global__ __launch_bounds__(256) void hist_kernel(const int* __restrict__ dst, int* __restrict__ counts) {
    int e = blockIdx.x * 256 + threadIdx.x;
    if (e < NE) atomicAdd(&counts[dst[e]], 1);
}

__global__ __launch_bounds__(1024) void scan1_kernel(const int* __restrict__ counts,
                                                     int* __restrict__ offs, int* __restrict__ bsums) {
    __shared__ int tmp[2][1024];
    int t = threadIdx.x;
    int g = blockIdx.x * 1024 + t;
    int v = (g < NN) ? counts[g] : 0;
    tmp[0][t] = v;
    __syncthreads();
    int pin = 0;
    for (int d = 1; d < 1024; d <<= 1) {
        int x = tmp[pin][t] + ((t >= d) ? tmp[pin][t - d] : 0);
        tmp[pin ^ 1][t] = x;
        pin ^= 1;
        __syncthreads();
    }
    int incl = tmp[pin][t];
    if (g < NN) offs[g] = incl - v;
    if (t == 1023) bsums[blockIdx.x] = incl;
}

__global__ __launch_bounds__(128) void scan2_kernel(int* __restrict__ bsums, int nb) {
    __shared__ int tmp[2][128];
    int t = threadIdx.x;
    int v = (t < nb) ? bsums[t] : 0;
    tmp[0][t] = v;
    __syncthreads();
    int pin = 0;
    for (int d = 1; d < 128; d <<= 1) {
        int x = tmp[pin][t] + ((t >= d) ? tmp[pin][t - d] : 0);
        tmp[pin ^ 1][t] = x;
        pin ^= 1;
        __syncthreads();
    }
    if (t < nb) bsums[t] = tmp[pin][t] - v;
}

__global__ __launch_bounds__(256) void scan3_kernel(int* __restrict__ offs, const int* __restrict__ bsums,
                                                    int* __restrict__ cursor) {
    int g = blockIdx.x * 256 + threadIdx.x;
    if (g < NN) {
        int o = offs[g] + bsums[g >> 10];
        offs[g] = o;
        cursor[g] = o;
    }
    if (g == 0) offs[NN] = NE;
}

// interleaved payload: one 8B store per edge
__global__ __launch_bounds__(256) void scatter_kernel(const int* __restrict__ src, const int* __restrict__ dst,
                                                      const float* __restrict__ ea, int* __restrict__ cursor,
                                                      int2* __restrict__ src_ea) {
    int e = blockIdx.x * 256 + threadIdx.x;
    if (e >= NE) return;
    int d = dst[e];
    int pos = atomicAdd(&cursor[d], 1);
    src_ea[pos] = make_int2(src[e], __float_as_int(ea[e]));
}

// ---------------- fused layer 0: BN-fold + gather-agg + GEMM + tanh ----------------
// 32 nodes per 512-thread block. t1 -> out[:,0:64]
__global__ __launch_bounds__(512) void gine0_kernel(const float* __restrict__ X,
        const int* __restrict__ offs, const int2* __restrict__ src_ea,
        const double* __restrict__ dsum, const double* __restrict__ dsq,
        const float* __restrict__ g, const float* __restrict__ b,
        const float* __restrict__ We, const float* __restrict__ be,
        const float* __restrict__ W, const float* __restrict__ bvec,
        float* __restrict__ out) {
    __shared__ __align__(16) float u_s[32][INC + 4];   // 16.9 KB
    __shared__ __align__(16) float w_s[DIM][INC + 4];  // 33.8 KB
    __shared__ float sc_s[INC], sh_s[INC];
    const int t = threadIdx.x;
    const int row0 = blockIdx.x * 32;
    bn_fold(t, INC, dsum, dsq, g, b, sc_s, sh_s);
    for (int i = t; i < INC * DIM; i += 512) {
        int k = i >> 6, c = i & 63;
        w_s[c][k] = W[i];
    }
    __syncthreads();
    // gather: 8 waves x 4 nodes
    const int wid = t >> 6, l = t & 63;
    const int c = l * 2;
    float2 sc = *(const float2*)(sc_s + c);
    float2 sh = *(const float2*)(sh_s + c);
    float2 wv = *(const float2*)(We + c);
    float2 bv = *(const float2*)(be + c);
    for (int nn = 0; nn < 4; ++nn) {
        int r = wid * 4 + nn;
        int n = row0 + r;
        float a0 = 0.f, a1 = 0.f;
        if (n < NN) {
            float2 x = *(const float2*)(X + (size_t)n * INC + c);
            a0 = fmaf(x.x, sc.x, sh.x);
            a1 = fmaf(x.y, sc.y, sh.y);
            int beg = offs[n], end = offs[n + 1];
            for (int base = beg; base < end; base += 64) {
                int j = base + l;
                int2 p = make_int2(0, 0);
                if (j < end) p = src_ea[j];
                float av = __int_as_float(p.y);
                int cnt = min(64, end - base);
                int tt = 0;
                for (; tt + 4 <= cnt; tt += 4) {
                    int s0 = __shfl(p.x, tt), s1 = __shfl(p.x, tt + 1), s2 = __shfl(p.x, tt + 2), s3 = __shfl(p.x, tt + 3);
                    float e0 = __shfl(av, tt), e1 = __shfl(av, tt + 1), e2 = __shfl(av, tt + 2), e3 = __shfl(av, tt + 3);
                    float2 x0 = *(const float2*)(X + (size_t)s0 * INC + c);
                    float2 x1 = *(const float2*)(X + (size_t)s1 * INC + c);
                    float2 x2 = *(const float2*)(X + (size_t)s2 * INC + c);
                    float2 x3 = *(const float2*)(X + (size_t)s3 * INC + c);
                    a0 += fmaxf(fmaf(x0.x, sc.x, sh.x) + fmaf(e0, wv.x, bv.x), 0.f);
                    a1 += fmaxf(fmaf(x0.y, sc.y, sh.y) + fmaf(e0, wv.y, bv.y), 0.f);
                    a0 += fmaxf(fmaf(x1.x, sc.x, sh.x) + fmaf(e1, wv.x, bv.x), 0.f);
                    a1 += fmaxf(fmaf(x1.y, sc.y, sh.y) + fmaf(e1, wv.y, bv.y), 0.f);
                    a0 += fmaxf(fmaf(x2.x, sc.x, sh.x) + fmaf(e2, wv.x, bv.x), 0.f);
                    a1 += fmaxf(fmaf(x2.y, sc.y, sh.y) + fmaf(e2, wv.y, bv.y), 0.f);
                    a0 += fmaxf(fmaf(x3.x, sc.x, sh.x) + fmaf(e3, wv.x, bv.x), 0.f);
                    a1 += fmaxf(fmaf(x3.y, sc.y, sh.y) + fmaf(e3, wv.y, bv.y), 0.f);
                }
                for (; tt < cnt; ++tt) {
                    int ss = __shfl(p.x, tt);
                    float aa = __shfl(av, tt);
                    float2 xv = *(const float2*)(X + (size_t)ss * INC + c);
                    a0 += fmaxf(fmaf(xv.x, sc.x, sh.x) + fmaf(aa, wv.x, bv.x), 0.f);
                    a1 += fmaxf(fmaf(xv.y, sc.y, sh.y) + fmaf(aa, wv.y, bv.y), 0.f);
                }
            }
        }
        *(float2*)&u_s[r][c] = make_float2(a0, a1);
    }
    __syncthreads();
    // GEMM: 32x64 outputs, 512 threads -> 4 outputs each
    const int cc = t & 15;
    const int rg = t >> 4;                 // row 0..31
    float acc0 = bvec[cc], acc1 = bvec[cc + 16], acc2 = bvec[cc + 32], acc3 = bvec[cc + 48];
    #pragma unroll 4
    for (int k = 0; k < INC; k += 4) {
        float4 w0 = *(const float4*)&w_s[cc][k];
        float4 w1 = *(const float4*)&w_s[cc + 16][k];
        float4 w2 = *(const float4*)&w_s[cc + 32][k];
        float4 w3 = *(const float4*)&w_s[cc + 48][k];
        float4 u = *(const float4*)&u_s[rg][k];
        acc0 = fmaf(u.x, w0.x, fmaf(u.y, w0.y, fmaf(u.z, w0.z, fmaf(u.w, w0.w, acc0))));
        acc1 = fmaf(u.x, w1.x, fmaf(u.y, w1.y, fmaf(u.z, w1.z, fmaf(u.w, w1.w, acc1))));
        acc2 = fmaf(u.x, w2.x, fmaf(u.y, w2.y, fmaf(u.z, w2.z, fmaf(u.w, w2.w, acc2))));
        acc3 = fmaf(u.x, w3.x, fmaf(u.y, w3.y, fmaf(u.z, w3.z, fmaf(u.w, w3.w, acc3))));
    }
    int rr = row0 + rg;
    if (rr < NN) {
        float* op = out + (size_t)rr * 192;
        op[cc]      = tanhf(acc0);
        op[cc + 16] = tanhf(acc1);
        op[cc + 32] = tanhf(acc2);
        op[cc + 48] = tanhf(acc3);
    }
}

// ---------------- normalize t1 -> h1 in place (folds finalize0) ----------------
__global__ __launch_bounds__(256) void norm_h1_kernel(float* __restrict__ io,
        const double* __restrict__ dsum, const double* __restrict__ dsq,
        const float* __restrict__ g, const float* __restrict__ b) {
    __shared__ float sc_s[DIM], sh_s[DIM];
    bn_fold(threadIdx.x, DIM, dsum, dsq, g, b, sc_s, sh_s);
    __syncthreads();
    size_t gidx = (size_t)blockIdx.x * 256 + threadIdx.x;
    size_t i4 = gidx * 4;
    if (i4 >= (size_t)NN * DIM) return;
    int c0 = (int)(i4 & 63);
    size_t n = i4 >> 6;
    float* p = io + n * 192 + c0;
    float4 v  = *(const float4*)p;
    float4 sc = *(const float4*)(sc_s + c0);
    float4 sh = *(const float4*)(sh_s + c0);
    v.x = fmaf(v.x, sc.x, sh.x);
    v.y = fmaf(v.y, sc.y, sh.y);
    v.z = fmaf(v.z, sc.z, sh.z);
    v.w = fmaf(v.w, sc.w, sh.w);
    *(float4*)p = v;
}

// ---------------- fused layer 1: gather-agg + GEMM + tanh ----------------
// 64 nodes per 512-thread block. h1 from out[:,0:64] (stride 192); t2 -> out[:,64:128]
__global__ __launch_bounds__(512) void gine1_kernel(const float* __restrict__ h1,
        const int* __restrict__ offs, const int2* __restrict__ src_ea,
        const float* __restrict__ We, const float* __restrict__ be,
        const float* __restrict__ W, const float* __restrict__ bvec,
        float* __restrict__ out) {
    __shared__ __align__(16) float u_s[64][DIM + 4];   // 17.4 KB
    __shared__ __align__(16) float w_s[DIM][DIM + 4];  // 17.4 KB
    const int t = threadIdx.x;
    const int row0 = blockIdx.x * 64;
    for (int i = t; i < DIM * DIM; i += 512) {
        int k = i >> 6, c = i & 63;
        w_s[c][k] = W[i];
    }
    const int wid = t >> 6, l = t & 63;
    float wv = We[l];
    float bv = be[l];
    for (int nn = 0; nn < 8; ++nn) {
        int r = wid * 8 + nn;
        int n = row0 + r;
        float acc = 0.f;
        if (n < NN) {
            acc = h1[(size_t)n * 192 + l];
            int beg = offs[n], end = offs[n + 1];
            for (int base = beg; base < end; base += 64) {
                int j = base + l;
                int2 p = make_int2(0, 0);
                if (j < end) p = src_ea[j];
                float av = __int_as_float(p.y);
                int cnt = min(64, end - base);
                int tt = 0;
                for (; tt + 4 <= cnt; tt += 4) {
                    int s0 = __shfl(p.x, tt), s1 = __shfl(p.x, tt + 1), s2 = __shfl(p.x, tt + 2), s3 = __shfl(p.x, tt + 3);
                    float e0 = __shfl(av, tt), e1 = __shfl(av, tt + 1), e2 = __shfl(av, tt + 2), e3 = __shfl(av, tt + 3);
                    float h0 = h1[(size_t)s0 * 192 + l];
                    float hA = h1[(size_t)s1 * 192 + l];
                    float hB = h1[(size_t)s2 * 192 + l];
                    float hC = h1[(size_t)s3 * 192 + l];
                    acc += fmaxf(h0 + fmaf(e0, wv, bv), 0.f);
                    acc += fmaxf(hA + fmaf(e1, wv, bv), 0.f);
                    acc += fmaxf(hB + fmaf(e2, wv, bv), 0.f);
                    acc += fmaxf(hC + fmaf(e3, wv, bv), 0.f);
                }
                for (; tt < cnt; ++tt) {
                    int ss = __shfl(p.x, tt);
                    float aa = __shfl(av, tt);
                    acc += fmaxf(h1[(size_t)ss * 192 + l] + fmaf(aa, wv, bv), 0.f);
                }
            }
        }
        u_s[r][l] = acc;
    }
    __syncthreads();
    // GEMM: 64x64 outputs, 512 threads -> 8 outputs each (2 rows x 4 cols)
    const int cc = t & 15;
    const int r0 = (t >> 4) * 2;
    float acc[2][4];
    #pragma unroll
    for (int j = 0; j < 4; j++) {
        float bj = bvec[cc + 16 * j];
        acc[0][j] = bj; acc[1][j] = bj;
    }
    #pragma unroll 4
    for (int k = 0; k < DIM; k += 4) {
        float4 w0 = *(const float4*)&w_s[cc][k];
        float4 w1 = *(const float4*)&w_s[cc + 16][k];
        float4 w2 = *(const float4*)&w_s[cc + 32][k];
        float4 w3 = *(const float4*)&w_s[cc + 48][k];
        #pragma unroll
        for (int i = 0; i < 2; i++) {
            float4 u = *(const float4*)&u_s[r0 + i][k];
            acc[i][0] = fmaf(u.x, w0.x, fmaf(u.y, w0.y, fmaf(u.z, w0.z, fmaf(u.w, w0.w, acc[i][0]))));
            acc[i][1] = fmaf(u.x, w1.x, fmaf(u.y, w1.y, fmaf(u.z, w1.z, fmaf(u.w, w1.w, acc[i][1]))));
            acc[i][2] = fmaf(u.x, w2.x, fmaf(u.y, w2.y, fmaf(u.z, w2.z, fmaf(u.w, w2.w, acc[i][2]))));
            acc[i][3] = fmaf(u.x, w3.x, fmaf(u.y, w3.y, fmaf(u.z, w3.z, fmaf(u.w, w3.w, acc[i][3]))));
        }
    }
    #pragma unroll
    for (int i = 0; i < 2; i++) {
        int rr = row0 + r0 + i;
        if (rr < NN) {
            float* op = out + (size_t)rr * 192 + 64;
            #pragma unroll
            for (int j = 0; j < 4; j++) op[cc + 16 * j] = tanhf(acc[i][j]);
        }
    }
}

// ---------------- fused: finalize1 + h2 = BN(t2) in place + h3 = tanh(h2 @ Wfc) ----------------
__global__ __launch_bounds__(256) void fc_kernel(float* __restrict__ io,
        const double* __restrict__ dsum, const double* __restrict__ dsq,
        const float* __restrict__ g, const float* __restrict__ b,
        const float* __restrict__ W) {
    __shared__ __align__(16) float u_s[64][DIM + 4];
    __shared__ __align__(16) float w_s[DIM][DIM + 4];
    __shared__ float sc_s[DIM], sh_s[DIM];
    const int t = threadIdx.x;
    const int row0 = blockIdx.x * 64;
    bn_fold(t, DIM, dsum, dsq, g, b, sc_s, sh_s);
    __syncthreads();
    for (int i = t; i < DIM * DIM; i += 256) {
        int k = i >> 6, c = i & 63;
        w_s[c][k] = W[i];
    }
    for (int i = t; i < 64 * DIM; i += 256) {
        int r = i >> 6, k = i & 63;
        int rr = row0 + r;
        float v = 0.f;
        if (rr < NN) {
            size_t idx = (size_t)rr * 192 + 64 + k;
            v = fmaf(io[idx], sc_s[k], sh_s[k]);
            io[idx] = v;                       // h2
        }
        u_s[r][k] = v;
    }
    __syncthreads();
    const int cc = t & 15;
    const int r0 = (t >> 4) << 2;
    float acc[4][4];
    #pragma unroll
    for (int j = 0; j < 4; j++) { acc[0][j] = 0.f; acc[1][j] = 0.f; acc[2][j] = 0.f; acc[3][j] = 0.f; }
    #pragma unroll 4
    for (int k = 0; k < DIM; k += 4) {
        float4 w0 = *(const float4*)&w_s[cc][k];
        float4 w1 = *(const float4*)&w_s[cc + 16][k];
        float4 w2 = *(const float4*)&w_s[cc + 32][k];
        float4 w3 = *(const float4*)&w_s[cc + 48][k];
        #pragma unroll
        for (int i = 0; i < 4; i++) {
            float4 u = *(const float4*)&u_s[r0 + i][k];
            acc[i][0] = fmaf(u.x, w0.x, fmaf(u.y, w0.y, fmaf(u.z, w0.z, fmaf(u.w, w0.w, acc[i][0]))));
            acc[i][1] = fmaf(u.x, w1.x, fmaf(u.y, w1.y, fmaf(u.z, w1.z, fmaf(u.w, w1.w, acc[i][1]))));
            acc[i][2] = fmaf(u.x, w2.x, fmaf(u.y, w2.y, fmaf(u.z, w2.z, fmaf(u.w, w2.w, acc[i][2]))));
            acc[i][3] = fmaf(u.x, w3.x, fmaf(u.y, w3.y, fmaf(u.z, w3.z, fmaf(u.w, w3.w, acc[i][3]))));
        }
    }
    #pragma unroll
    for (int i = 0; i < 4; i++) {
        int rr = row0 + r0 + i;
        if (rr < NN) {
            #pragma unroll
            for (int j = 0; j < 4; j++)
                io[(size_t)rr * 192 + 128 + cc + 16 * j] = tanhf(acc[i][j]);
        }
    }
}

extern "C" void kernel_launch(void* const* d_in, const int* in_sizes, int n_in,
                              void* d_out, int out_size, void* d_ws, size_t ws_size,
                              hipStream_t stream) {
    const float* X      = (const float*)d_in[0];
    const int*   ei     = (const int*)  d_in[1];
    const float* ea     = (const float*)d_in[2];
    const float* bng    = (const float*)d_in[3];
    const float* bnb    = (const float*)d_in[4];
    const float* We0    = (const float*)d_in[5];
    const float* be0    = (const float*)d_in[6];
    const float* W0     = (const float*)d_in[7];
    const float* b0     = (const float*)d_in[8];
    const float* bn0g   = (const float*)d_in[9];
    const float* bn0b   = (const float*)d_in[10];
    const float* We1    = (const float*)d_in[11];
    const float* be1    = (const float*)d_in[12];
    const float* W1     = (const float*)d_in[13];
    const float* b1     = (const float*)d_in[14];
    const float* bn1g   = (const float*)d_in[15];
    const float* bn1b   = (const float*)d_in[16];
    const float* Wfc    = (const float*)d_in[17];

    const int* src = ei;
    const int* dst = ei + NE;
    float* out = (float*)d_out;

    // ---- workspace layout (~14 MB) ----
    int2* src_ea  = (int2*)d_ws;                        // NE
    int*  counts  = (int*)(src_ea + NE);                // NN
    int*  offs    = counts + NN;                        // NN+1
    int*  cursor  = offs + NN + 1;                      // NN
    int*  bsums   = cursor + NN;                        // 128
    double* dstats = (double*)(((uintptr_t)(bsums + 128) + 15) & ~(uintptr_t)15);
    double* dsum_in = dstats;        double* dsq_in = dstats + 128;
    double* dsum0   = dstats + 256;  double* dsq0   = dstats + 320;
    double* dsum1   = dstats + 384;  double* dsq1   = dstats + 448;

    hipMemsetAsync(counts, 0, NN * sizeof(int), stream);
    hipMemsetAsync(dstats, 0, 512 * sizeof(double), stream);

    // input BN stats
    stats_kernel<INC><<<512, 256, 0, stream>>>(X, NN, INC, dsum_in, dsq_in);

    // CSR build (shared by both layers)
    const int NB = (NN + 1023) / 1024;   // 98
    hist_kernel<<<NE / 256, 256, 0, stream>>>(dst, counts);
    scan1_kernel<<<NB, 1024, 0, stream>>>(counts, offs, bsums);
    scan2_kernel<<<1, 128, 0, stream>>>(bsums, NB);
    scan3_kernel<<<(NN + 255) / 256, 256, 0, stream>>>(offs, bsums, cursor);
    scatter_kernel<<<NE / 256, 256, 0, stream>>>(src, dst, ea, cursor, src_ea);

    // layer 0 (fused finalize_in + agg + GEMM)
    gine0_kernel<<<(NN + 31) / 32, 512, 0, stream>>>(X, offs, src_ea, dsum_in, dsq_in, bng, bnb,
                                                     We0, be0, W0, b0, out);
    stats_kernel<DIM><<<512, 256, 0, stream>>>(out, NN, 192, dsum0, dsq0);
    norm_h1_kernel<<<(NN * DIM / 4 + 255) / 256, 256, 0, stream>>>(out, dsum0, dsq0, bn0g, bn0b);

    // layer 1 (fused agg + GEMM)
    gine1_kernel<<<(NN + 63) / 64, 512, 0, stream>>>(out, offs, src_ea, We1, be1, W1, b1, out);
    stats_kernel<DIM><<<512, 256, 0, stream>>>(out + 64, NN, 192, dsum1, dsq1);

    // h2 (in place) + h3 (fused finalize1)
    fc_kernel<<<(NN + 63) / 64, 256, 0, stream>>>(out, dsum1, dsq1, bn1g, bn1b, Wfc);
}

// Round 4
// 580.983 us; speedup vs baseline: 7.4010x; 1.0338x over previous
//
#include <hip/hip_runtime.h>
#include <math.h>
#include <stdint.h>

#define NN 100000
#define NE 1600000
#define INC 128
#define DIM 64
#define EPS 1e-5f
#define SB 512   // stats blocks inside fused stats+hist kernel

// ---------------- per-channel stats (sum, sumsq) in f64 ----------------
template<int C>
__global__ __launch_bounds__(256) void stats_kernel(const float* __restrict__ in, int n, int stride,
                                                    double* __restrict__ sum_out, double* __restrict__ sq_out) {
    const int RPB = 256 / C;             // rows per block step
    int c  = threadIdx.x % C;
    int rl = threadIdx.x / C;
    int row = blockIdx.x * RPB + rl;
    int rstride = gridDim.x * RPB;
    double s = 0.0, q = 0.0;
    for (int r = row; r < n; r += rstride) {
        double v = (double)in[(size_t)r * stride + c];
        s += v; q += v * v;
    }
    __shared__ double ls[256], lq[256];
    ls[threadIdx.x] = s; lq[threadIdx.x] = q;
    __syncthreads();
    if (rl == 0) {
        #pragma unroll
        for (int i = 1; i < RPB; i++) { s += ls[i * C + c]; q += lq[i * C + c]; }
        atomicAdd(&sum_out[c], s);
        atomicAdd(&sq_out[c], q);
    }
}

// fused: blocks [0,SB) do X stats (C=128); blocks [SB,...) do dst histogram
__global__ __launch_bounds__(256) void stats_hist_kernel(const float* __restrict__ X,
        const int* __restrict__ dst, int* __restrict__ counts,
        double* __restrict__ sum_out, double* __restrict__ sq_out) {
    __shared__ double ls[256], lq[256];
    if (blockIdx.x < SB) {
        int c  = threadIdx.x & 127;
        int rl = threadIdx.x >> 7;           // 2 rows per block step
        int row = blockIdx.x * 2 + rl;
        const int rstride = SB * 2;
        double s = 0.0, q = 0.0;
        for (int r = row; r < NN; r += rstride) {
            double v = (double)X[(size_t)r * INC + c];
            s += v; q += v * v;
        }
        ls[threadIdx.x] = s; lq[threadIdx.x] = q;
        __syncthreads();
        if (rl == 0) {
            s += ls[128 + c]; q += lq[128 + c];
            atomicAdd(&sum_out[c], s);
            atomicAdd(&sq_out[c], q);
        }
    } else {
        int e = (blockIdx.x - SB) * 256 + threadIdx.x;
        if (e < NE) atomicAdd(&counts[dst[e]], 1);
    }
}

// BN scale/shift from f64 stats (device helper, computed redundantly per block)
__device__ inline void bn_fold(int t, int C, const double* dsum, const double* dsq,
                               const float* g, const float* b, float* sc_s, float* sh_s) {
    if (t < C) {
        double m = dsum[t] / (double)NN;
        double v = dsq[t] / (double)NN - m * m;
        double sc = (double)g[t] / sqrt(v + (double)EPS);
        sc_s[t] = (float)sc;
        sh_s[t] = (float)((double)b[t] - m * sc);
    }
}

// ---------------- CSR build: scan / scatter ----------------
__global__ __launch_bounds__(1024) void scan1_kernel(const int* __restrict__ counts,
                                                     int* __restrict__ offs, int* __restrict__ bsums) {
    __shared__ int tmp[2][1024];
    int t = threadIdx.x;
    int g = blockIdx.x * 1024 + t;
    int v = (g < NN) ? counts[g] : 0;
    tmp[0][t] = v;
    __syncthreads();
    int pin = 0;
    for (int d = 1; d < 1024; d <<= 1) {
        int x = tmp[pin][t] + ((t >= d) ? tmp[pin][t - d] : 0);
        tmp[pin ^ 1][t] = x;
        pin ^= 1;
        __syncthreads();
    }
    int incl = tmp[pin][t];
    if (g < NN) offs[g] = incl - v;
    if (t == 1023) bsums[blockIdx.x] = incl;
}

__global__ __launch_bounds__(128) void scan2_kernel(int* __restrict__ bsums, int nb) {
    __shared__ int tmp[2][128];
    int t = threadIdx.x;
    int v = (t < nb) ? bsums[t] : 0;
    tmp[0][t] = v;
    __syncthreads();
    int pin = 0;
    for (int d = 1; d < 128; d <<= 1) {
        int x = tmp[pin][t] + ((t >= d) ? tmp[pin][t - d] : 0);
        tmp[pin ^ 1][t] = x;
        pin ^= 1;
        __syncthreads();
    }
    if (t < nb) bsums[t] = tmp[pin][t] - v;
}

__global__ __launch_bounds__(256) void scan3_kernel(int* __restrict__ offs, const int* __restrict__ bsums,
                                                    int* __restrict__ cursor) {
    int g = blockIdx.x * 256 + threadIdx.x;
    if (g < NN) {
        int o = offs[g] + bsums[g >> 10];
        offs[g] = o;
        cursor[g] = o;
    }
    if (g == 0) offs[NN] = NE;
}

// interleaved payload: one 8B store per edge
__global__ __launch_bounds__(256) void scatter_kernel(const int* __restrict__ src, const int* __restrict__ dst,
                                                      const float* __restrict__ ea, int* __restrict__ cursor,
                                                      int2* __restrict__ src_ea) {
    int e = blockIdx.x * 256 + threadIdx.x;
    if (e >= NE) return;
    int d = dst[e];
    int pos = atomicAdd(&cursor[d], 1);
    src_ea[pos] = make_int2(src[e], __float_as_int(ea[e]));
}

// ---------------- fused layer 0: BN-fold + gather-agg (half-wave) + GEMM + tanh ----------------
// 32 nodes per 512-thread block. t1 -> out[:,0:64]
__global__ __launch_bounds__(512) void gine0_kernel(const float* __restrict__ X,
        const int* __restrict__ offs, const int2* __restrict__ src_ea,
        const double* __restrict__ dsum, const double* __restrict__ dsq,
        const float* __restrict__ g, const float* __restrict__ b,
        const float* __restrict__ We, const float* __restrict__ be,
        const float* __restrict__ W, const float* __restrict__ bvec,
        float* __restrict__ out) {
    __shared__ __align__(16) float u_s[32][INC + 4];   // 16.9 KB
    __shared__ __align__(16) float w_s[DIM][INC + 4];  // 33.8 KB
    __shared__ float sc_s[INC], sh_s[INC];
    const int t = threadIdx.x;
    const int row0 = blockIdx.x * 32;
    bn_fold(t, INC, dsum, dsq, g, b, sc_s, sh_s);
    for (int i = t; i < INC * DIM; i += 512) {
        int k = i >> 6, c = i & 63;
        w_s[c][k] = W[i];
    }
    __syncthreads();
    // gather: 8 waves x 4 nodes; within a wave, halves process 2 edges at a time
    const int wid = t >> 6, l = t & 63;
    const int half = l >> 5;
    const int c4 = (l & 31) * 4;
    float4 sc = *(const float4*)(sc_s + c4);
    float4 sh = *(const float4*)(sh_s + c4);
    float4 wv = *(const float4*)(We + c4);
    float4 bv = *(const float4*)(be + c4);
    for (int nn = 0; nn < 4; ++nn) {
        int r = wid * 4 + nn;
        int n = row0 + r;
        float a0 = 0.f, a1 = 0.f, a2 = 0.f, a3 = 0.f;
        if (n < NN) {
            int beg = offs[n], end = offs[n + 1];
            for (int base = beg; base < end; base += 64) {
                int j = base + l;
                int2 p = (j < end) ? src_ea[j] : make_int2(0, 0);
                float avf = __int_as_float(p.y);
                int cnt = min(64, end - base);
                int tt = 0;
                for (; tt + 4 <= cnt; tt += 4) {
                    int e0 = tt + half, e1 = tt + 2 + half;
                    int s0 = __shfl(p.x, e0), s1 = __shfl(p.x, e1);
                    float av0 = __shfl(avf, e0), av1 = __shfl(avf, e1);
                    float4 x0 = *(const float4*)(X + (size_t)s0 * INC + c4);
                    float4 x1 = *(const float4*)(X + (size_t)s1 * INC + c4);
                    a0 += fmaxf(fmaf(x0.x, sc.x, sh.x) + fmaf(av0, wv.x, bv.x), 0.f);
                    a1 += fmaxf(fmaf(x0.y, sc.y, sh.y) + fmaf(av0, wv.y, bv.y), 0.f);
                    a2 += fmaxf(fmaf(x0.z, sc.z, sh.z) + fmaf(av0, wv.z, bv.z), 0.f);
                    a3 += fmaxf(fmaf(x0.w, sc.w, sh.w) + fmaf(av0, wv.w, bv.w), 0.f);
                    a0 += fmaxf(fmaf(x1.x, sc.x, sh.x) + fmaf(av1, wv.x, bv.x), 0.f);
                    a1 += fmaxf(fmaf(x1.y, sc.y, sh.y) + fmaf(av1, wv.y, bv.y), 0.f);
                    a2 += fmaxf(fmaf(x1.z, sc.z, sh.z) + fmaf(av1, wv.z, bv.z), 0.f);
                    a3 += fmaxf(fmaf(x1.w, sc.w, sh.w) + fmaf(av1, wv.w, bv.w), 0.f);
                }
                for (; tt < cnt; tt += 2) {
                    int e0 = tt + half;
                    int es = min(e0, cnt - 1);
                    int s0 = __shfl(p.x, es);
                    float av0 = __shfl(avf, es);
                    if (e0 < cnt) {
                        float4 x0 = *(const float4*)(X + (size_t)s0 * INC + c4);
                        a0 += fmaxf(fmaf(x0.x, sc.x, sh.x) + fmaf(av0, wv.x, bv.x), 0.f);
                        a1 += fmaxf(fmaf(x0.y, sc.y, sh.y) + fmaf(av0, wv.y, bv.y), 0.f);
                        a2 += fmaxf(fmaf(x0.z, sc.z, sh.z) + fmaf(av0, wv.z, bv.z), 0.f);
                        a3 += fmaxf(fmaf(x0.w, sc.w, sh.w) + fmaf(av0, wv.w, bv.w), 0.f);
                    }
                }
            }
        }
        // combine halves, add self term, store (lower half writes the full row)
        a0 += __shfl_xor(a0, 32);
        a1 += __shfl_xor(a1, 32);
        a2 += __shfl_xor(a2, 32);
        a3 += __shfl_xor(a3, 32);
        if (half == 0) {
            if (n < NN) {
                float4 x = *(const float4*)(X + (size_t)n * INC + c4);
                a0 += fmaf(x.x, sc.x, sh.x);
                a1 += fmaf(x.y, sc.y, sh.y);
                a2 += fmaf(x.z, sc.z, sh.z);
                a3 += fmaf(x.w, sc.w, sh.w);
            }
            *(float4*)&u_s[r][c4] = make_float4(a0, a1, a2, a3);
        }
    }
    __syncthreads();
    // GEMM: 32x64 outputs, 512 threads -> 4 outputs each
    const int cc = t & 15;
    const int rg = t >> 4;                 // row 0..31
    float acc0 = bvec[cc], acc1 = bvec[cc + 16], acc2 = bvec[cc + 32], acc3 = bvec[cc + 48];
    #pragma unroll 4
    for (int k = 0; k < INC; k += 4) {
        float4 w0 = *(const float4*)&w_s[cc][k];
        float4 w1 = *(const float4*)&w_s[cc + 16][k];
        float4 w2 = *(const float4*)&w_s[cc + 32][k];
        float4 w3 = *(const float4*)&w_s[cc + 48][k];
        float4 u = *(const float4*)&u_s[rg][k];
        acc0 = fmaf(u.x, w0.x, fmaf(u.y, w0.y, fmaf(u.z, w0.z, fmaf(u.w, w0.w, acc0))));
        acc1 = fmaf(u.x, w1.x, fmaf(u.y, w1.y, fmaf(u.z, w1.z, fmaf(u.w, w1.w, acc1))));
        acc2 = fmaf(u.x, w2.x, fmaf(u.y, w2.y, fmaf(u.z, w2.z, fmaf(u.w, w2.w, acc2))));
        acc3 = fmaf(u.x, w3.x, fmaf(u.y, w3.y, fmaf(u.z, w3.z, fmaf(u.w, w3.w, acc3))));
    }
    int rr = row0 + rg;
    if (rr < NN) {
        float* op = out + (size_t)rr * 192;
        op[cc]      = tanhf(acc0);
        op[cc + 16] = tanhf(acc1);
        op[cc + 32] = tanhf(acc2);
        op[cc + 48] = tanhf(acc3);
    }
}

// ---------------- normalize t1 -> h1 in place (folds finalize0) ----------------
__global__ __launch_bounds__(256) void norm_h1_kernel(float* __restrict__ io,
        const double* __restrict__ dsum, const double* __restrict__ dsq,
        const float* __restrict__ g, const float* __restrict__ b) {
    __shared__ float sc_s[DIM], sh_s[DIM];
    bn_fold(threadIdx.x, DIM, dsum, dsq, g, b, sc_s, sh_s);
    __syncthreads();
    size_t gidx = (size_t)blockIdx.x * 256 + threadIdx.x;
    size_t i4 = gidx * 4;
    if (i4 >= (size_t)NN * DIM) return;
    int c0 = (int)(i4 & 63);
    size_t n = i4 >> 6;
    float* p = io + n * 192 + c0;
    float4 v  = *(const float4*)p;
    float4 sc = *(const float4*)(sc_s + c0);
    float4 sh = *(const float4*)(sh_s + c0);
    v.x = fmaf(v.x, sc.x, sh.x);
    v.y = fmaf(v.y, sc.y, sh.y);
    v.z = fmaf(v.z, sc.z, sh.z);
    v.w = fmaf(v.w, sc.w, sh.w);
    *(float4*)p = v;
}

// ---------------- fused layer 1: gather-agg (half-wave) + GEMM + tanh ----------------
// 64 nodes per 512-thread block. h1 from out[:,0:64] (stride 192); t2 -> out[:,64:128]
__global__ __launch_bounds__(512) void gine1_kernel(const float* __restrict__ h1,
        const int* __restrict__ offs, const int2* __restrict__ src_ea,
        const float* __restrict__ We, const float* __restrict__ be,
        const float* __restrict__ W, const float* __restrict__ bvec,
        float* __restrict__ out) {
    __shared__ __align__(16) float u_s[64][DIM + 4];   // 17.4 KB
    __shared__ __align__(16) float w_s[DIM][DIM + 4];  // 17.4 KB
    const int t = threadIdx.x;
    const int row0 = blockIdx.x * 64;
    for (int i = t; i < DIM * DIM; i += 512) {
        int k = i >> 6, c = i & 63;
        w_s[c][k] = W[i];
    }
    const int wid = t >> 6, l = t & 63;
    const int half = l >> 5;
    const int c2 = (l & 31) * 2;
    float2 wv = *(const float2*)(We + c2);
    float2 bv = *(const float2*)(be + c2);
    for (int nn = 0; nn < 8; ++nn) {
        int r = wid * 8 + nn;
        int n = row0 + r;
        float a0 = 0.f, a1 = 0.f;
        if (n < NN) {
            int beg = offs[n], end = offs[n + 1];
            for (int base = beg; base < end; base += 64) {
                int j = base + l;
                int2 p = (j < end) ? src_ea[j] : make_int2(0, 0);
                float avf = __int_as_float(p.y);
                int cnt = min(64, end - base);
                int tt = 0;
                for (; tt + 8 <= cnt; tt += 8) {
                    int e0 = tt + half, e1 = tt + 2 + half, e2 = tt + 4 + half, e3 = tt + 6 + half;
                    int s0 = __shfl(p.x, e0), s1 = __shfl(p.x, e1), s2 = __shfl(p.x, e2), s3 = __shfl(p.x, e3);
                    float av0 = __shfl(avf, e0), av1 = __shfl(avf, e1), av2 = __shfl(avf, e2), av3 = __shfl(avf, e3);
                    float2 h0 = *(const float2*)(h1 + (size_t)s0 * 192 + c2);
                    float2 hA = *(const float2*)(h1 + (size_t)s1 * 192 + c2);
                    float2 hB = *(const float2*)(h1 + (size_t)s2 * 192 + c2);
                    float2 hC = *(const float2*)(h1 + (size_t)s3 * 192 + c2);
                    a0 += fmaxf(h0.x + fmaf(av0, wv.x, bv.x), 0.f);
                    a1 += fmaxf(h0.y + fmaf(av0, wv.y, bv.y), 0.f);
                    a0 += fmaxf(hA.x + fmaf(av1, wv.x, bv.x), 0.f);
                    a1 += fmaxf(hA.y + fmaf(av1, wv.y, bv.y), 0.f);
                    a0 += fmaxf(hB.x + fmaf(av2, wv.x, bv.x), 0.f);
                    a1 += fmaxf(hB.y + fmaf(av2, wv.y, bv.y), 0.f);
                    a0 += fmaxf(hC.x + fmaf(av3, wv.x, bv.x), 0.f);
                    a1 += fmaxf(hC.y + fmaf(av3, wv.y, bv.y), 0.f);
                }
                for (; tt < cnt; tt += 2) {
                    int e0 = tt + half;
                    int es = min(e0, cnt - 1);
                    int s0 = __shfl(p.x, es);
                    float av0 = __shfl(avf, es);
                    if (e0 < cnt) {
                        float2 h0 = *(const float2*)(h1 + (size_t)s0 * 192 + c2);
                        a0 += fmaxf(h0.x + fmaf(av0, wv.x, bv.x), 0.f);
                        a1 += fmaxf(h0.y + fmaf(av0, wv.y, bv.y), 0.f);
                    }
                }
            }
        }
        a0 += __shfl_xor(a0, 32);
        a1 += __shfl_xor(a1, 32);
        if (half == 0) {
            if (n < NN) {
                float2 h = *(const float2*)(h1 + (size_t)n * 192 + c2);
                a0 += h.x;
                a1 += h.y;
            }
            *(float2*)&u_s[r][c2] = make_float2(a0, a1);
        }
    }
    __syncthreads();
    // GEMM: 64x64 outputs, 512 threads -> 8 outputs each (2 rows x 4 cols)
    const int cc = t & 15;
    const int r0 = (t >> 4) * 2;
    float acc[2][4];
    #pragma unroll
    for (int j = 0; j < 4; j++) {
        float bj = bvec[cc + 16 * j];
        acc[0][j] = bj; acc[1][j] = bj;
    }
    #pragma unroll 4
    for (int k = 0; k < DIM; k += 4) {
        float4 w0 = *(const float4*)&w_s[cc][k];
        float4 w1 = *(const float4*)&w_s[cc + 16][k];
        float4 w2 = *(const float4*)&w_s[cc + 32][k];
        float4 w3 = *(const float4*)&w_s[cc + 48][k];
        #pragma unroll
        for (int i = 0; i < 2; i++) {
            float4 u = *(const float4*)&u_s[r0 + i][k];
            acc[i][0] = fmaf(u.x, w0.x, fmaf(u.y, w0.y, fmaf(u.z, w0.z, fmaf(u.w, w0.w, acc[i][0]))));
            acc[i][1] = fmaf(u.x, w1.x, fmaf(u.y, w1.y, fmaf(u.z, w1.z, fmaf(u.w, w1.w, acc[i][1]))));
            acc[i][2] = fmaf(u.x, w2.x, fmaf(u.y, w2.y, fmaf(u.z, w2.z, fmaf(u.w, w2.w, acc[i][2]))));
            acc[i][3] = fmaf(u.x, w3.x, fmaf(u.y, w3.y, fmaf(u.z, w3.z, fmaf(u.w, w3.w, acc[i][3]))));
        }
    }
    #pragma unroll
    for (int i = 0; i < 2; i++) {
        int rr = row0 + r0 + i;
        if (rr < NN) {
            float* op = out + (size_t)rr * 192 + 64;
            #pragma unroll
            for (int j = 0; j < 4; j++) op[cc + 16 * j] = tanhf(acc[i][j]);
        }
    }
}

// ---------------- fused: finalize1 + h2 = BN(t2) in place + h3 = tanh(h2 @ Wfc) ----------------
__global__ __launch_bounds__(256) void fc_kernel(float* __restrict__ io,
        const double* __restrict__ dsum, const double* __restrict__ dsq,
        const float* __restrict__ g, const float* __restrict__ b,
        const float* __restrict__ W) {
    __shared__ __align__(16) float u_s[64][DIM + 4];
    __shared__ __align__(16) float w_s[DIM][DIM + 4];
    __shared__ float sc_s[DIM], sh_s[DIM];
    const int t = threadIdx.x;
    const int row0 = blockIdx.x * 64;
    bn_fold(t, DIM, dsum, dsq, g, b, sc_s, sh_s);
    __syncthreads();
    for (int i = t; i < DIM * DIM; i += 256) {
        int k = i >> 6, c = i & 63;
        w_s[c][k] = W[i];
    }
    for (int i = t; i < 64 * DIM; i += 256) {
        int r = i >> 6, k = i & 63;
        int rr = row0 + r;
        float v = 0.f;
        if (rr < NN) {
            size_t idx = (size_t)rr * 192 + 64 + k;
            v = fmaf(io[idx], sc_s[k], sh_s[k]);
            io[idx] = v;                       // h2
        }
        u_s[r][k] = v;
    }
    __syncthreads();
    const int cc = t & 15;
    const int r0 = (t >> 4) << 2;
    float acc[4][4];
    #pragma unroll
    for (int j = 0; j < 4; j++) { acc[0][j] = 0.f; acc[1][j] = 0.f; acc[2][j] = 0.f; acc[3][j] = 0.f; }
    #pragma unroll 4
    for (int k = 0; k < DIM; k += 4) {
        float4 w0 = *(const float4*)&w_s[cc][k];
        float4 w1 = *(const float4*)&w_s[cc + 16][k];
        float4 w2 = *(const float4*)&w_s[cc + 32][k];
        float4 w3 = *(const float4*)&w_s[cc + 48][k];
        #pragma unroll
        for (int i = 0; i < 4; i++) {
            float4 u = *(const float4*)&u_s[r0 + i][k];
            acc[i][0] = fmaf(u.x, w0.x, fmaf(u.y, w0.y, fmaf(u.z, w0.z, fmaf(u.w, w0.w, acc[i][0]))));
            acc[i][1] = fmaf(u.x, w1.x, fmaf(u.y, w1.y, fmaf(u.z, w1.z, fmaf(u.w, w1.w, acc[i][1]))));
            acc[i][2] = fmaf(u.x, w2.x, fmaf(u.y, w2.y, fmaf(u.z, w2.z, fmaf(u.w, w2.w, acc[i][2]))));
            acc[i][3] = fmaf(u.x, w3.x, fmaf(u.y, w3.y, fmaf(u.z, w3.z, fmaf(u.w, w3.w, acc[i][3]))));
        }
    }
    #pragma unroll
    for (int i = 0; i < 4; i++) {
        int rr = row0 + r0 + i;
        if (rr < NN) {
            #pragma unroll
            for (int j = 0; j < 4; j++)
                io[(size_t)rr * 192 + 128 + cc + 16 * j] = tanhf(acc[i][j]);
        }
    }
}

extern "C" void kernel_launch(void* const* d_in, const int* in_sizes, int n_in,
                              void* d_out, int out_size, void* d_ws, size_t ws_size,
                              hipStream_t stream) {
    const float* X      = (const float*)d_in[0];
    const int*   ei     = (const int*)  d_in[1];
    const float* ea     = (const float*)d_in[2];
    const float* bng    = (const float*)d_in[3];
    const float* bnb    = (const float*)d_in[4];
    const float* We0    = (const float*)d_in[5];
    const float* be0    = (const float*)d_in[6];
    const float* W0     = (const float*)d_in[7];
    const float* b0     = (const float*)d_in[8];
    const float* bn0g   = (const float*)d_in[9];
    const float* bn0b   = (const float*)d_in[10];
    const float* We1    = (const float*)d_in[11];
    const float* be1    = (const float*)d_in[12];
    const float* W1     = (const float*)d_in[13];
    const float* b1     = (const float*)d_in[14];
    const float* bn1g   = (const float*)d_in[15];
    const float* bn1b   = (const float*)d_in[16];
    const float* Wfc    = (const float*)d_in[17];

    const int* src = ei;
    const int* dst = ei + NE;
    float* out = (float*)d_out;

    // ---- workspace layout (~14 MB) ----
    int2* src_ea  = (int2*)d_ws;                        // NE
    int*  counts  = (int*)(src_ea + NE);                // NN
    int*  offs    = counts + NN;                        // NN+1
    int*  cursor  = offs + NN + 1;                      // NN
    int*  bsums   = cursor + NN;                        // 128
    double* dstats = (double*)(((uintptr_t)(bsums + 128) + 15) & ~(uintptr_t)15);
    double* dsum_in = dstats;        double* dsq_in = dstats + 128;
    double* dsum0   = dstats + 256;  double* dsq0   = dstats + 320;
    double* dsum1   = dstats + 384;  double* dsq1   = dstats + 448;

    hipMemsetAsync(counts, 0, NN * sizeof(int), stream);
    hipMemsetAsync(dstats, 0, 512 * sizeof(double), stream);

    // fused input-BN stats + dst histogram
    stats_hist_kernel<<<SB + (NE + 255) / 256, 256, 0, stream>>>(X, dst, counts, dsum_in, dsq_in);

    // CSR build (shared by both layers)
    const int NB = (NN + 1023) / 1024;   // 98
    scan1_kernel<<<NB, 1024, 0, stream>>>(counts, offs, bsums);
    scan2_kernel<<<1, 128, 0, stream>>>(bsums, NB);
    scan3_kernel<<<(NN + 255) / 256, 256, 0, stream>>>(offs, bsums, cursor);
    scatter_kernel<<<NE / 256, 256, 0, stream>>>(src, dst, ea, cursor, src_ea);

    // layer 0 (fused finalize_in + agg + GEMM)
    gine0_kernel<<<(NN + 31) / 32, 512, 0, stream>>>(X, offs, src_ea, dsum_in, dsq_in, bng, bnb,
                                                     We0, be0, W0, b0, out);
    stats_kernel<DIM><<<512, 256, 0, stream>>>(out, NN, 192, dsum0, dsq0);
    norm_h1_kernel<<<(NN * DIM / 4 + 255) / 256, 256, 0, stream>>>(out, dsum0, dsq0, bn0g, bn0b);

    // layer 1 (fused agg + GEMM)
    gine1_kernel<<<(NN + 63) / 64, 512, 0, stream>>>(out, offs, src_ea, We1, be1, W1, b1, out);
    stats_kernel<DIM><<<512, 256, 0, stream>>>(out + 64, NN, 192, dsum1, dsq1);

    // h2 (in place) + h3 (fused finalize1)
    fc_kernel<<<(NN + 63) / 64, 256, 0, stream>>>(out, dsum1, dsq1, bn1g, bn1b, Wfc);
}